// Round 14
// baseline (1795.774 us; speedup 1.0000x reference)
//
#include <hip/hip_runtime.h>
#include <math.h>

// Problem constants
constexpr int kB    = 2048;
constexpr int kA    = 8;
constexpr int kEin  = 64;
constexpr int kEout = 256;
constexpr int kH    = 1024;
constexpr int kV    = 1024;
constexpr int kL    = 16;
constexpr int kKin  = kA * kEin;      // 512
constexpr int kNG   = 4 * kH;         // 4096 gate cols
constexpr float kInvLo = 1.0f / 2048.0f;

using half8 = __attribute__((ext_vector_type(8))) _Float16;
using half4 = __attribute__((ext_vector_type(4))) _Float16;
using f32x4 = __attribute__((ext_vector_type(4))) float;
using u64   = unsigned long long;

// async global->LDS (used only by one-time eg_gemm)
#define GLL16(g, l) __builtin_amdgcn_global_load_lds(                        \
    (const __attribute__((address_space(1))) void*)(g),                      \
    (__attribute__((address_space(3))) void*)(l), 16, 0, 0)

__device__ __forceinline__ float sigm(float x) { return 1.0f / (1.0f + expf(-x)); }

// fp32 -> fp16 hi + fp16 lo (x ~= hi + lo/2048), ~22 significant bits
struct HL { _Float16 hi, lo; };
__device__ __forceinline__ HL split2v(float x) {
  HL r;
  r.hi = (_Float16)x;
  r.lo = (_Float16)((x - (float)r.hi) * 2048.0f);
  return r;
}

// Packed fragment layout (128-row blocks, NKS k-steps of 32): elem (m,k) ->
//   ((((m>>7)*NKS + (k>>5))*4 + ((k>>3)&3))*128 + (m&127))*8 + (k&7)
__device__ __forceinline__ size_t packAK(int m, int k, int nks) {
  return ((((size_t)(m >> 7) * nks + (k >> 5)) * 4 + ((k >> 3) & 3)) * 128 + (m & 127)) * 8 + (k & 7);
}

// argmax key: sortable-float major, (1023-idx) minor -> max key == numpy first-max
__device__ __forceinline__ u64 amax_key(float v, int idx) {
  unsigned b = __float_as_uint(v);
  unsigned u = (b & 0x80000000u) ? ~b : (b | 0x80000000u);
  return ((u64)u << 10) | (unsigned)(1023 - idx);
}
__device__ __forceinline__ int key_sym(u64 k) {
  return k == 0 ? kV : 1023 - (int)(k & 1023);   // 0 = never-written = SOS row
}

// ---------------------------------------------------------------- init state
__global__ __launch_bounds__(256) void init_state(float* __restrict__ c,
                                                  u64* __restrict__ keys) {
  int i = blockIdx.x * 256 + threadIdx.x;
  c[i] = 0.0f;
  if (i < 17 * kB) keys[i] = 0ull;
}

// -------------------------------------------------- plain fp32 -> hi/lo split
__global__ __launch_bounds__(256) void split_plain(const float* __restrict__ src,
                                                   _Float16* __restrict__ hi,
                                                   _Float16* __restrict__ lo,
                                                   int n4) {
  int i = blockIdx.x * 256 + threadIdx.x;
  if (i >= n4) return;
  float4 v = ((const float4*)src)[i];
  half4 h, l;
  HL s0 = split2v(v.x), s1 = split2v(v.y), s2 = split2v(v.z), s3 = split2v(v.w);
  h.x = s0.hi; l.x = s0.lo; h.y = s1.hi; l.y = s1.lo;
  h.z = s2.hi; l.z = s2.lo; h.w = s3.hi; l.w = s3.lo;
  *(half4*)(hi + (size_t)i * 4) = h;
  *(half4*)(lo + (size_t)i * 4) = l;
}

// --------------- gates weights: gate-permute + split. k<256 (W_ih part) goes
// row-major [n][256] (for eg_gemm); k>=256 (W_hh part) goes packed fragments.
__global__ __launch_bounds__(320) void split_gates_w(const float* __restrict__ W_ih,
                                                     const float* __restrict__ W_hh,
                                                     _Float16* __restrict__ rm_hi,
                                                     _Float16* __restrict__ rm_lo,
                                                     _Float16* __restrict__ p_hi,
                                                     _Float16* __restrict__ p_lo) {
  const int n  = blockIdx.x;
  const int k4 = threadIdx.x * 4;
  const int g  = (n >> 4) & 3;
  const int j  = ((n >> 6) << 4) | (n & 15);
  const int src = g * kH + j;
  float4 v = (k4 < kEout) ? *(const float4*)&W_ih[(size_t)src * kEout + k4]
                          : *(const float4*)&W_hh[(size_t)src * kH + (k4 - kEout)];
  half4 h, l;
  HL s0 = split2v(v.x), s1 = split2v(v.y), s2 = split2v(v.z), s3 = split2v(v.w);
  h.x = s0.hi; l.x = s0.lo; h.y = s1.hi; l.y = s1.lo;
  h.z = s2.hi; l.z = s2.lo; h.w = s3.hi; l.w = s3.lo;
  if (k4 < kEout) {
    *(half4*)(rm_hi + (size_t)n * kEout + k4) = h;
    *(half4*)(rm_lo + (size_t)n * kEout + k4) = l;
  } else {
    const size_t ad = packAK(n, k4 - kEout, 32);
    *(half4*)(p_hi + ad) = h;
    *(half4*)(p_lo + ad) = l;
  }
}

// ------------------- W_out -> split + packed fragments (32-row n-blocks)
__global__ __launch_bounds__(256) void split_pack_wo(const float* __restrict__ W_out,
                                                     _Float16* __restrict__ hi,
                                                     _Float16* __restrict__ lo) {
  const int n  = blockIdx.x;            // 0..1023
  const int k4 = threadIdx.x * 4;       // 0..1023
  float4 v = *(const float4*)&W_out[(size_t)n * kH + k4];
  half4 h, l;
  HL s0 = split2v(v.x), s1 = split2v(v.y), s2 = split2v(v.z), s3 = split2v(v.w);
  h.x = s0.hi; l.x = s0.lo; h.y = s1.hi; l.y = s1.lo;
  h.z = s2.hi; l.z = s2.lo; h.w = s3.hi; l.w = s3.lo;
  const size_t ad = ((((size_t)(n >> 5) * 32 + (k4 >> 5)) * 4 + ((k4 >> 3) & 3)) * 32
                     + (n & 31)) * 8 + (k4 & 7);
  *(half4*)(hi + ad) = h;
  *(half4*)(lo + ad) = l;
}

// ------------- pack A0 = in_emb[x] gathered, split, packed (K=512, 16 ks)
__global__ __launch_bounds__(128) void pack_a0(const int* __restrict__ x,
                                               const float* __restrict__ in_emb,
                                               _Float16* __restrict__ hi,
                                               _Float16* __restrict__ lo) {
  const int m  = blockIdx.x;            // 0..2047
  const int k4 = threadIdx.x * 4;       // 0..511
  const int idx = x[m * kA + (k4 >> 6)];
  float4 v = *(const float4*)&in_emb[(size_t)idx * kEin + (k4 & 63)];
  half4 h, l;
  HL s0 = split2v(v.x), s1 = split2v(v.y), s2 = split2v(v.z), s3 = split2v(v.w);
  h.x = s0.hi; l.x = s0.lo; h.y = s1.hi; l.y = s1.lo;
  h.z = s2.hi; l.z = s2.lo; h.w = s3.hi; l.w = s3.lo;
  const size_t ad = packAK(m, k4, 16);
  *(half4*)(hi + ad) = h;
  *(half4*)(lo + ad) = l;
}

// ------------- pack W_in: [1024][512] -> split packed fragments (K=512, 16 ks)
__global__ __launch_bounds__(128) void pack_w0(const float* __restrict__ W_in,
                                               _Float16* __restrict__ hi,
                                               _Float16* __restrict__ lo) {
  const int n  = blockIdx.x;            // 0..1023
  const int k4 = threadIdx.x * 4;       // 0..511
  float4 v = *(const float4*)&W_in[(size_t)n * kKin + k4];
  half4 h, l;
  HL s0 = split2v(v.x), s1 = split2v(v.y), s2 = split2v(v.z), s3 = split2v(v.w);
  h.x = s0.hi; l.x = s0.lo; h.y = s1.hi; l.y = s1.lo;
  h.z = s2.hi; l.z = s2.lo; h.w = s3.hi; l.w = s3.lo;
  const size_t ad = packAK(n, k4, 16);
  *(half4*)(hi + ad) = h;
  *(half4*)(lo + ad) = l;
}

// -------- h0 = ie @ W_in^T + b_in, register-direct fp16x2 3-pass (one-time).
__global__ __launch_bounds__(256, 2) void h0_mfma(
    const _Float16* __restrict__ a_hi, const _Float16* __restrict__ a_lo,
    const _Float16* __restrict__ w_hi, const _Float16* __restrict__ w_lo,
    const float* __restrict__ b_in,
    _Float16* __restrict__ h_hi, _Float16* __restrict__ h_lo) {
  const int t    = threadIdx.x;
  const int bx   = blockIdx.x;                 // m block (16)
  const int by   = blockIdx.y;                 // n block (8)
  const int lane = t & 63, wid = t >> 6;
  const int wm   = (wid >> 1) * 64;
  const int wnv  = wid & 1;
  const int lc   = lane & 15, lg = lane >> 4;
  constexpr int SK = 4 * 128 * 8;              // 4096

  size_t adr_a = (size_t)bx * 16 * SK + ((size_t)lg * 128 + wm + lc) * 8;
  size_t adr_b = (size_t)by * 16 * SK + ((size_t)lg * 128 + wnv * 64 + lc) * 8;

  f32x4 acc1[4][4] = {}; f32x4 acc2[4][4] = {};
  for (int ks = 0; ks < 16; ++ks) {
    half8 ah[4], al[4], bh[4], bl[4];
#pragma unroll
    for (int mf = 0; mf < 4; ++mf) {
      ah[mf] = *(const half8*)(a_hi + adr_a + mf * 128);
      al[mf] = *(const half8*)(a_lo + adr_a + mf * 128);
    }
#pragma unroll
    for (int nf = 0; nf < 4; ++nf) {
      bh[nf] = *(const half8*)(w_hi + adr_b + nf * 128);
      bl[nf] = *(const half8*)(w_lo + adr_b + nf * 128);
    }
#pragma unroll
    for (int mf = 0; mf < 4; ++mf)
#pragma unroll
      for (int nf = 0; nf < 4; ++nf) {
        acc1[mf][nf] = __builtin_amdgcn_mfma_f32_16x16x32_f16(ah[mf], bh[nf], acc1[mf][nf], 0, 0, 0);
        acc2[mf][nf] = __builtin_amdgcn_mfma_f32_16x16x32_f16(ah[mf], bl[nf], acc2[mf][nf], 0, 0, 0);
        acc2[mf][nf] = __builtin_amdgcn_mfma_f32_16x16x32_f16(al[mf], bh[nf], acc2[mf][nf], 0, 0, 0);
      }
    adr_a += SK; adr_b += SK;
  }
#pragma unroll
  for (int mf = 0; mf < 4; ++mf)
#pragma unroll
    for (int reg = 0; reg < 4; ++reg) {
      const int gm = bx * 128 + wm + mf * 16 + lg * 4 + reg;
#pragma unroll
      for (int nf = 0; nf < 4; ++nf) {
        const int j = by * 128 + wnv * 64 + nf * 16 + lc;
        HL s = split2v(acc1[mf][nf][reg] + acc2[mf][nf][reg] * kInvLo + b_in[j]);
        const size_t ad = packAK(gm, j, 32);
        h_hi[ad] = s.hi; h_lo[ad] = s.lo;
      }
    }
}

// ------------- Eg = out_emb @ (W_ih gate-permuted)^T, fp16x2 3-pass, one-time.
__global__ __launch_bounds__(256, 2) void eg_gemm(
    const _Float16* __restrict__ oe_hi, const _Float16* __restrict__ oe_lo,
    const _Float16* __restrict__ Wg_hi, const _Float16* __restrict__ Wg_lo,
    float* __restrict__ Eg) {
  __shared__ __align__(16) _Float16 Ah[4][128][8], Al[4][128][8],
                                    Bh[4][128][8], Bl[4][128][8];
  const int t    = threadIdx.x;
  const int m0   = blockIdx.x * 128;
  const int by   = blockIdx.y;
  const int n0   = by * 128;
  const int r    = t & 127, q = t >> 7;
  const int rw   = r & 64;
  const int lane = t & 63, wid = t >> 6;
  const int wm   = (wid >> 1) * 64;
  const int wnv  = wid & 1;
  const int lc   = lane & 15, lg = lane >> 4;
  f32x4 acc1[4][4] = {}; f32x4 acc2[4][4] = {};
  for (int k0 = 0; k0 < kEout; k0 += 32) {
    const size_t oa = (size_t)(m0 + r) * kEout + k0 + q * 16;
    const size_t ob = (size_t)(n0 + r) * kEout + k0 + q * 16;
    __syncthreads();
    GLL16(oe_hi + oa,     &Ah[2*q  ][rw][0]);
    GLL16(oe_hi + oa + 8, &Ah[2*q+1][rw][0]);
    GLL16(oe_lo + oa,     &Al[2*q  ][rw][0]);
    GLL16(oe_lo + oa + 8, &Al[2*q+1][rw][0]);
    GLL16(Wg_hi + ob,     &Bh[2*q  ][rw][0]);
    GLL16(Wg_hi + ob + 8, &Bh[2*q+1][rw][0]);
    GLL16(Wg_lo + ob,     &Bl[2*q  ][rw][0]);
    GLL16(Wg_lo + ob + 8, &Bl[2*q+1][rw][0]);
    __syncthreads();
    half8 ah[4], al[4], bh[4], bl[4];
#pragma unroll
    for (int mf = 0; mf < 4; ++mf) {
      ah[mf] = *(const half8*)&Ah[lg][wm + mf*16 + lc][0];
      al[mf] = *(const half8*)&Al[lg][wm + mf*16 + lc][0];
    }
#pragma unroll
    for (int nf = 0; nf < 4; ++nf) {
      bh[nf] = *(const half8*)&Bh[lg][wnv*64 + nf*16 + lc][0];
      bl[nf] = *(const half8*)&Bl[lg][wnv*64 + nf*16 + lc][0];
    }
#pragma unroll
    for (int mf = 0; mf < 4; ++mf)
#pragma unroll
      for (int nf = 0; nf < 4; ++nf) {
        acc1[mf][nf] = __builtin_amdgcn_mfma_f32_16x16x32_f16(ah[mf], bh[nf], acc1[mf][nf], 0, 0, 0);
        acc2[mf][nf] = __builtin_amdgcn_mfma_f32_16x16x32_f16(ah[mf], bl[nf], acc2[mf][nf], 0, 0, 0);
        acc2[mf][nf] = __builtin_amdgcn_mfma_f32_16x16x32_f16(al[mf], bh[nf], acc2[mf][nf], 0, 0, 0);
      }
  }
#pragma unroll
  for (int mf = 0; mf < 4; ++mf)
#pragma unroll
    for (int reg = 0; reg < 4; ++reg) {
      const int m = m0 + wm + mf * 16 + lg * 4 + reg;
#pragma unroll
      for (int nf = 0; nf < 4; ++nf)
        Eg[(size_t)m * kNG + n0 + wnv*64 + nf*16 + lc] =
            acc1[mf][nf][reg] + acc2[mf][nf][reg] * kInvLo;
    }
}

// ----------------- Eg row kV = sos @ W_ih^T (gate-permuted cols), exact fp32
__global__ __launch_bounds__(256) void gs_row(const float* __restrict__ sos,
                                              const float* __restrict__ W_ih,
                                              float* __restrict__ Eg) {
  const int n = blockIdx.x * 256 + threadIdx.x;   // 0..4095
  const int g = (n >> 4) & 3;
  const int j = ((n >> 6) << 4) | (n & 15);
  const float* w = W_ih + (size_t)(g * kH + j) * kEout;
  float s = 0.0f;
#pragma unroll 4
  for (int k = 0; k < kEout; k += 4) {
    float4 wv = *(const float4*)&w[k];
    float4 sv = *(const float4*)&sos[k];
    s += wv.x*sv.x + wv.y*sv.y + wv.z*sv.z + wv.w*sv.w;
  }
  Eg[(size_t)kV * kNG + n] = s;
}

// --------- gates GEMM: barrier-free register-direct, XCD-locality remap.
// XCD x (lin&7) owns 8 by-panels -> its B slice (16MB/8 = 2MB) stays
// L2-resident for the whole dispatch; bx is held for 8 consecutive blocks so
// the A slice (0.5MB) is L2-hot in its window. Both operands ~L2-hit ->
// load latency coverable by 3 waves/SIMD TLP.
__global__ __launch_bounds__(256, 3) void gates_lstm_mfma(
    const _Float16* __restrict__ hp_hi,  const _Float16* __restrict__ hp_lo,
    const _Float16* __restrict__ Wgp_hi, const _Float16* __restrict__ Wgp_lo,
    const float* __restrict__ Eg,        const u64* __restrict__ keys,
    const float* __restrict__ b_ih, const float* __restrict__ b_hh,
    float* __restrict__ c,
    _Float16* __restrict__ ho_hi, _Float16* __restrict__ ho_lo,
    float* __restrict__ seq, int t) {
  const int tid  = threadIdx.x;
  const int lin  = blockIdx.y * 16 + blockIdx.x;  // 0..1023
  const int xcd  = lin & 7;
  const int ii   = lin >> 3;                      // 0..127
  const int by   = xcd * 8 + (ii & 7);            // 0..63 (8 panels per XCD)
  const int bx   = ii >> 3;                       // 0..15 (8-block A window)
  const int m0   = bx * 128;
  const int lane = tid & 63, wid = tid >> 6;
  const int wm   = wid * 32;                   // wave m offset
  const int lc   = lane & 15, lg = lane >> 4;
  constexpr int SK = 4 * 128 * 8;              // 4096 halfs per k-step block

  size_t adr_a = (size_t)bx * 32 * SK + ((size_t)lg * 128 + wm + lc) * 8;
  size_t adr_b = (size_t)(by >> 1) * 32 * SK
               + ((size_t)lg * 128 + (by & 1) * 64 + lc) * 8;

  f32x4 acc1[2][4] = {}; f32x4 acc2[2][4] = {};
#pragma unroll 2
  for (int ks = 0; ks < 32; ++ks) {
    half8 ah[2], al[2], bh[4], bl[4];
#pragma unroll
    for (int mf = 0; mf < 2; ++mf) {
      ah[mf] = *(const half8*)(hp_hi + adr_a + mf * 128);
      al[mf] = *(const half8*)(hp_lo + adr_a + mf * 128);
    }
#pragma unroll
    for (int nf = 0; nf < 4; ++nf) {
      bh[nf] = *(const half8*)(Wgp_hi + adr_b + nf * 128);
      bl[nf] = *(const half8*)(Wgp_lo + adr_b + nf * 128);
    }
#pragma unroll
    for (int mf = 0; mf < 2; ++mf)
#pragma unroll
      for (int nf = 0; nf < 4; ++nf) {
        acc1[mf][nf] = __builtin_amdgcn_mfma_f32_16x16x32_f16(ah[mf], bh[nf], acc1[mf][nf], 0, 0, 0);
        acc2[mf][nf] = __builtin_amdgcn_mfma_f32_16x16x32_f16(ah[mf], bl[nf], acc2[mf][nf], 0, 0, 0);
        acc2[mf][nf] = __builtin_amdgcn_mfma_f32_16x16x32_f16(al[mf], bh[nf], acc2[mf][nf], 0, 0, 0);
      }
    adr_a += SK; adr_b += SK;
  }
  // epilogue: j = by*16 + lc; 4 n-frags = 4 gates (i,f,g,o); Eg[sym] gather;
  // packed h output; seq[t-1] write from decoded keys (by==0 blocks).
  const int j     = by * 16 + lc;
  const int nbase = by * 64 + lc;              // Eg col for nf: nbase + nf*16
  const int jks = j >> 5, jq = (j >> 3) & 3, je = j & 7;
  float bb[4];
#pragma unroll
  for (int nf = 0; nf < 4; ++nf) bb[nf] = b_ih[nf * kH + j] + b_hh[nf * kH + j];
#pragma unroll
  for (int mf = 0; mf < 2; ++mf)
#pragma unroll
    for (int reg = 0; reg < 4; ++reg) {
      const int lr = wm + mf * 16 + lg * 4 + reg;   // local row 0..127
      const int m  = m0 + lr;
      const size_t off = (size_t)m * kH + j;
      const int s = key_sym(keys[m]);               // prev-step argmax decode
      if (by == 0 && lc == 0 && t > 0)
        seq[(size_t)m * kL + (t - 1)] = (float)(s);
      const float* Erow = Eg + (size_t)s * kNG + nbase;
      const float vi = acc1[mf][0][reg] + acc2[mf][0][reg] * kInvLo + bb[0] + Erow[0];
      const float vf = acc1[mf][1][reg] + acc2[mf][1][reg] * kInvLo + bb[1] + Erow[16];
      const float vg = acc1[mf][2][reg] + acc2[mf][2][reg] * kInvLo + bb[2] + Erow[32];
      const float vo = acc1[mf][3][reg] + acc2[mf][3][reg] * kInvLo + bb[3] + Erow[48];
      const float cn = sigm(vf) * c[off] + sigm(vi) * tanhf(vg);
      const float hn = sigm(vo) * tanhf(cn);
      c[off] = cn;
      HL sp = split2v(hn);
      const size_t ad = ((((size_t)bx * 32 + jks) * 4 + jq) * 128 + lr) * 8 + je;
      ho_hi[ad] = sp.hi; ho_lo[ad] = sp.lo;
    }
}

// ----------- logits: barrier-free register-direct; 128x32 tile, grid 16x32.
// XCD remap: xcd owns 4 by-panels (Wop slice 0.5MB L2-resident); bx held for
// 4 consecutive blocks. Fused argmax partial via atomicMax(u64 key).
__global__ __launch_bounds__(256, 3) void logits_mfma(
    const _Float16* __restrict__ hp_hi, const _Float16* __restrict__ hp_lo,
    const _Float16* __restrict__ Wop_hi, const _Float16* __restrict__ Wop_lo,
    const float* __restrict__ b_out, float* __restrict__ out,
    u64* __restrict__ keys) {
  const int t    = threadIdx.x;
  const int lin  = blockIdx.y * 16 + blockIdx.x;  // 0..511
  const int xcd  = lin & 7;
  const int ii   = lin >> 3;                      // 0..63
  const int by   = xcd * 4 + (ii & 3);            // 0..31
  const int bx   = ii >> 2;                       // 0..15
  const int lane = t & 63, wid = t >> 6;
  const int wm   = wid * 32;
  const int lc   = lane & 15, lg = lane >> 4;
  constexpr int SKA = 4 * 128 * 8;             // 4096
  constexpr int SKB = 4 * 32 * 8;              // 1024

  size_t adr_a = (size_t)bx * 32 * SKA + ((size_t)lg * 128 + wm + lc) * 8;
  size_t adr_b = (size_t)by * 32 * SKB + ((size_t)lg * 32 + lc) * 8;

  f32x4 acc1[2][2] = {}; f32x4 acc2[2][2] = {};
#pragma unroll 2
  for (int ks = 0; ks < 32; ++ks) {
    half8 ah[2], al[2], bh[2], bl[2];
#pragma unroll
    for (int mf = 0; mf < 2; ++mf) {
      ah[mf] = *(const half8*)(hp_hi + adr_a + mf * 128);
      al[mf] = *(const half8*)(hp_lo + adr_a + mf * 128);
    }
#pragma unroll
    for (int nf = 0; nf < 2; ++nf) {
      bh[nf] = *(const half8*)(Wop_hi + adr_b + nf * 128);
      bl[nf] = *(const half8*)(Wop_lo + adr_b + nf * 128);
    }
#pragma unroll
    for (int mf = 0; mf < 2; ++mf)
#pragma unroll
      for (int nf = 0; nf < 2; ++nf) {
        acc1[mf][nf] = __builtin_amdgcn_mfma_f32_16x16x32_f16(ah[mf], bh[nf], acc1[mf][nf], 0, 0, 0);
        acc2[mf][nf] = __builtin_amdgcn_mfma_f32_16x16x32_f16(ah[mf], bl[nf], acc2[mf][nf], 0, 0, 0);
        acc2[mf][nf] = __builtin_amdgcn_mfma_f32_16x16x32_f16(al[mf], bh[nf], acc2[mf][nf], 0, 0, 0);
      }
    adr_a += SKA; adr_b += SKB;
  }
#pragma unroll
  for (int mf = 0; mf < 2; ++mf)
#pragma unroll
    for (int reg = 0; reg < 4; ++reg) {
      const int m = bx * 128 + wm + mf * 16 + lg * 4 + reg;
      float v[2];
#pragma unroll
      for (int nf = 0; nf < 2; ++nf) {
        const int n = by * 32 + nf * 16 + lc;
        v[nf] = acc1[mf][nf][reg] + acc2[mf][nf][reg] * kInvLo + b_out[n];
        out[(size_t)m * (kL * kV) + n] = v[nf];
      }
      float bv = v[0]; int bi = by * 32 + lc;
      if (v[1] > bv) { bv = v[1]; bi = by * 32 + 16 + lc; }   // strict >: first-max
#pragma unroll
      for (int off = 1; off < 16; off <<= 1) {
        const float ov = __shfl_xor(bv, off);
        const int   oi = __shfl_xor(bi, off);
        if (ov > bv || (ov == bv && oi < bi)) { bv = ov; bi = oi; }
      }
      if (lc == 0) atomicMax(&keys[m], amax_key(bv, bi));
    }
}

// --------------------------------- final step's seq write from keys[16]
__global__ __launch_bounds__(256) void final_decode(const u64* __restrict__ keys,
                                                    float* __restrict__ seq) {
  const int b = blockIdx.x * 256 + threadIdx.x;
  if (b >= kB) return;
  const u64 k = keys[b];
  seq[(size_t)b * kL + (kL - 1)] = (float)(k == 0 ? 0 : 1023 - (int)(k & 1023));
}

// ---------------------------------------------------------------------------
extern "C" void kernel_launch(void* const* d_in, const int* in_sizes, int n_in,
                              void* d_out, int out_size, void* d_ws, size_t ws_size,
                              hipStream_t stream) {
  const int*   x       = (const int*)d_in[0];
  const float* in_emb  = (const float*)d_in[1];
  const float* out_emb = (const float*)d_in[2];
  const float* W_in    = (const float*)d_in[3];
  const float* b_in    = (const float*)d_in[4];
  const float* W_ih    = (const float*)d_in[5];
  const float* b_ih    = (const float*)d_in[6];
  const float* W_hh    = (const float*)d_in[7];
  const float* b_hh    = (const float*)d_in[8];
  const float* W_out   = (const float*)d_in[9];
  const float* b_out   = (const float*)d_in[10];
  const float* sos     = (const float*)d_in[11];

  // workspace layout
  float* cb  = (float*)d_ws;                           // [B,H] fp32 cell state
  float* Eg  = cb + (size_t)kB * kH;                   // [V+1][4096] fp32
  u64*  keys = (u64*)(Eg + (size_t)(kV + 1) * kNG);    // [17][B] argmax keys
  _Float16* hp = (_Float16*)(keys + 17 * (size_t)kB);
  const size_t nBH = (size_t)kB * kH;                  // 2097152
  _Float16* hA_hi  = hp;            _Float16* hA_lo  = hp + nBH;     // packed
  _Float16* hB_hi  = hp + 2*nBH;    _Float16* hB_lo  = hp + 3*nBH;   // packed
  _Float16* Wgrm_hi = hp + 4*nBH;                       // [4096][256] row-major
  _Float16* Wgrm_lo = Wgrm_hi + (size_t)kNG*kEout;
  _Float16* Wgp_hi  = Wgrm_lo + (size_t)kNG*kEout;      // packed [4096 x 1024]
  _Float16* Wgp_lo  = Wgp_hi + (size_t)kNG*kH;
  _Float16* Wop_hi  = Wgp_lo + (size_t)kNG*kH;          // packed [1024 x 1024]
  _Float16* Wop_lo  = Wop_hi + (size_t)kV*kH;
  _Float16* oe_hi   = Wop_lo + (size_t)kV*kH;           // [1024][256] row-major
  _Float16* oe_lo   = oe_hi + (size_t)kV*kEout;
  _Float16* A0_hi   = oe_lo + (size_t)kV*kEout;         // packed [2048 x 512]
  _Float16* A0_lo   = A0_hi + (size_t)kB*kKin;
  _Float16* W0_hi   = A0_lo + (size_t)kB*kKin;          // packed [1024 x 512]
  _Float16* W0_lo   = W0_hi + (size_t)kH*kKin;

  float* seq    = (float*)d_out;                       // [B,L]
  float* logits = seq + (size_t)kB * kL;               // [B,L,V]

  init_state<<<(kB * kH) / 256, 256, 0, stream>>>(cb, keys);
  split_gates_w<<<kNG, 320, 0, stream>>>(W_ih, W_hh, Wgrm_hi, Wgrm_lo, Wgp_hi, Wgp_lo);
  split_pack_wo<<<kV, 256, 0, stream>>>(W_out, Wop_hi, Wop_lo);
  split_plain<<<(kV * kEout / 4) / 256, 256, 0, stream>>>(out_emb, oe_hi, oe_lo, kV * kEout / 4);
  pack_a0<<<kB, 128, 0, stream>>>(x, in_emb, A0_hi, A0_lo);
  pack_w0<<<kH, 128, 0, stream>>>(W_in, W0_hi, W0_lo);
  eg_gemm<<<dim3(kV / 128, kNG / 128), 256, 0, stream>>>(oe_hi, oe_lo, Wgrm_hi, Wgrm_lo, Eg);
  gs_row<<<kNG / 256, 256, 0, stream>>>(sos, W_ih, Eg);
  h0_mfma<<<dim3(kB / 128, kH / 128), 256, 0, stream>>>(A0_hi, A0_lo, W0_hi, W0_lo, b_in, hA_hi, hA_lo);

  for (int t = 0; t < kL; ++t) {
    const _Float16* hi_h = (t & 1) ? hB_hi : hA_hi;
    const _Float16* hi_l = (t & 1) ? hB_lo : hA_lo;
    _Float16* ho_h = (t & 1) ? hA_hi : hB_hi;
    _Float16* ho_l = (t & 1) ? hA_lo : hB_lo;
    gates_lstm_mfma<<<dim3(kB / 128, kNG / 64), 256, 0, stream>>>(
        hi_h, hi_l, Wgp_hi, Wgp_lo, Eg, keys + (size_t)t * kB,
        b_ih, b_hh, cb, ho_h, ho_l, seq, t);
    logits_mfma<<<dim3(kB / 128, kV / 32), 256, 0, stream>>>(
        ho_h, ho_l, Wop_hi, Wop_lo, b_out, logits + (size_t)t * kV,
        keys + (size_t)(t + 1) * kB);
  }
  final_decode<<<kB / 256, 256, 0, stream>>>(keys + 16 * (size_t)kB, seq);
}

// Round 15
// 1725.036 us; speedup vs baseline: 1.0410x; 1.0410x over previous
//
#include <hip/hip_runtime.h>
#include <math.h>

// Problem constants
constexpr int kB    = 2048;
constexpr int kA    = 8;
constexpr int kEin  = 64;
constexpr int kEout = 256;
constexpr int kH    = 1024;
constexpr int kV    = 1024;
constexpr int kL    = 16;
constexpr int kKin  = kA * kEin;      // 512
constexpr int kNG   = 4 * kH;         // 4096 gate cols
constexpr float kInvLo = 1.0f / 2048.0f;

using half8 = __attribute__((ext_vector_type(8))) _Float16;
using half4 = __attribute__((ext_vector_type(4))) _Float16;
using f32x4 = __attribute__((ext_vector_type(4))) float;
using u64   = unsigned long long;

// async global->LDS (used only by one-time eg_gemm)
#define GLL16(g, l) __builtin_amdgcn_global_load_lds(                        \
    (const __attribute__((address_space(1))) void*)(g),                      \
    (__attribute__((address_space(3))) void*)(l), 16, 0, 0)

__device__ __forceinline__ float sigm(float x) { return 1.0f / (1.0f + expf(-x)); }

// fp32 -> fp16 hi + fp16 lo (x ~= hi + lo/2048), ~22 significant bits
struct HL { _Float16 hi, lo; };
__device__ __forceinline__ HL split2v(float x) {
  HL r;
  r.hi = (_Float16)x;
  r.lo = (_Float16)((x - (float)r.hi) * 2048.0f);
  return r;
}

// Packed fragment layout (128-row blocks, NKS k-steps of 32): elem (m,k) ->
//   ((((m>>7)*NKS + (k>>5))*4 + ((k>>3)&3))*128 + (m&127))*8 + (k&7)
__device__ __forceinline__ size_t packAK(int m, int k, int nks) {
  return ((((size_t)(m >> 7) * nks + (k >> 5)) * 4 + ((k >> 3) & 3)) * 128 + (m & 127)) * 8 + (k & 7);
}

// argmax key: sortable-float major, (1023-idx) minor -> max key == numpy first-max
__device__ __forceinline__ u64 amax_key(float v, int idx) {
  unsigned b = __float_as_uint(v);
  unsigned u = (b & 0x80000000u) ? ~b : (b | 0x80000000u);
  return ((u64)u << 10) | (unsigned)(1023 - idx);
}
__device__ __forceinline__ int key_sym(u64 k) {
  return k == 0 ? kV : 1023 - (int)(k & 1023);   // 0 = never-written = SOS row
}

// ---------------------------------------------------------------- init state
__global__ __launch_bounds__(256) void init_state(float* __restrict__ c,
                                                  u64* __restrict__ keys) {
  int i = blockIdx.x * 256 + threadIdx.x;
  c[i] = 0.0f;
  if (i < 17 * kB) keys[i] = 0ull;
}

// -------------------------------------------------- plain fp32 -> hi/lo split
__global__ __launch_bounds__(256) void split_plain(const float* __restrict__ src,
                                                   _Float16* __restrict__ hi,
                                                   _Float16* __restrict__ lo,
                                                   int n4) {
  int i = blockIdx.x * 256 + threadIdx.x;
  if (i >= n4) return;
  float4 v = ((const float4*)src)[i];
  half4 h, l;
  HL s0 = split2v(v.x), s1 = split2v(v.y), s2 = split2v(v.z), s3 = split2v(v.w);
  h.x = s0.hi; l.x = s0.lo; h.y = s1.hi; l.y = s1.lo;
  h.z = s2.hi; l.z = s2.lo; h.w = s3.hi; l.w = s3.lo;
  *(half4*)(hi + (size_t)i * 4) = h;
  *(half4*)(lo + (size_t)i * 4) = l;
}

// --------------- gates weights: gate-permute + split. k<256 (W_ih part) goes
// row-major [n][256] (for eg_gemm); k>=256 (W_hh part) goes packed fragments.
__global__ __launch_bounds__(320) void split_gates_w(const float* __restrict__ W_ih,
                                                     const float* __restrict__ W_hh,
                                                     _Float16* __restrict__ rm_hi,
                                                     _Float16* __restrict__ rm_lo,
                                                     _Float16* __restrict__ p_hi,
                                                     _Float16* __restrict__ p_lo) {
  const int n  = blockIdx.x;
  const int k4 = threadIdx.x * 4;
  const int g  = (n >> 4) & 3;
  const int j  = ((n >> 6) << 4) | (n & 15);
  const int src = g * kH + j;
  float4 v = (k4 < kEout) ? *(const float4*)&W_ih[(size_t)src * kEout + k4]
                          : *(const float4*)&W_hh[(size_t)src * kH + (k4 - kEout)];
  half4 h, l;
  HL s0 = split2v(v.x), s1 = split2v(v.y), s2 = split2v(v.z), s3 = split2v(v.w);
  h.x = s0.hi; l.x = s0.lo; h.y = s1.hi; l.y = s1.lo;
  h.z = s2.hi; l.z = s2.lo; h.w = s3.hi; l.w = s3.lo;
  if (k4 < kEout) {
    *(half4*)(rm_hi + (size_t)n * kEout + k4) = h;
    *(half4*)(rm_lo + (size_t)n * kEout + k4) = l;
  } else {
    const size_t ad = packAK(n, k4 - kEout, 32);
    *(half4*)(p_hi + ad) = h;
    *(half4*)(p_lo + ad) = l;
  }
}

// ------------------- W_out -> split + packed fragments (32-row n-blocks)
__global__ __launch_bounds__(256) void split_pack_wo(const float* __restrict__ W_out,
                                                     _Float16* __restrict__ hi,
                                                     _Float16* __restrict__ lo) {
  const int n  = blockIdx.x;            // 0..1023
  const int k4 = threadIdx.x * 4;       // 0..1023
  float4 v = *(const float4*)&W_out[(size_t)n * kH + k4];
  half4 h, l;
  HL s0 = split2v(v.x), s1 = split2v(v.y), s2 = split2v(v.z), s3 = split2v(v.w);
  h.x = s0.hi; l.x = s0.lo; h.y = s1.hi; l.y = s1.lo;
  h.z = s2.hi; l.z = s2.lo; h.w = s3.hi; l.w = s3.lo;
  const size_t ad = ((((size_t)(n >> 5) * 32 + (k4 >> 5)) * 4 + ((k4 >> 3) & 3)) * 32
                     + (n & 31)) * 8 + (k4 & 7);
  *(half4*)(hi + ad) = h;
  *(half4*)(lo + ad) = l;
}

// ------------- pack A0 = in_emb[x] gathered, split, packed (K=512, 16 ks)
__global__ __launch_bounds__(128) void pack_a0(const int* __restrict__ x,
                                               const float* __restrict__ in_emb,
                                               _Float16* __restrict__ hi,
                                               _Float16* __restrict__ lo) {
  const int m  = blockIdx.x;            // 0..2047
  const int k4 = threadIdx.x * 4;       // 0..511
  const int idx = x[m * kA + (k4 >> 6)];
  float4 v = *(const float4*)&in_emb[(size_t)idx * kEin + (k4 & 63)];
  half4 h, l;
  HL s0 = split2v(v.x), s1 = split2v(v.y), s2 = split2v(v.z), s3 = split2v(v.w);
  h.x = s0.hi; l.x = s0.lo; h.y = s1.hi; l.y = s1.lo;
  h.z = s2.hi; l.z = s2.lo; h.w = s3.hi; l.w = s3.lo;
  const size_t ad = packAK(m, k4, 16);
  *(half4*)(hi + ad) = h;
  *(half4*)(lo + ad) = l;
}

// ------------- pack W_in: [1024][512] -> split packed fragments (K=512, 16 ks)
__global__ __launch_bounds__(128) void pack_w0(const float* __restrict__ W_in,
                                               _Float16* __restrict__ hi,
                                               _Float16* __restrict__ lo) {
  const int n  = blockIdx.x;            // 0..1023
  const int k4 = threadIdx.x * 4;       // 0..511
  float4 v = *(const float4*)&W_in[(size_t)n * kKin + k4];
  half4 h, l;
  HL s0 = split2v(v.x), s1 = split2v(v.y), s2 = split2v(v.z), s3 = split2v(v.w);
  h.x = s0.hi; l.x = s0.lo; h.y = s1.hi; l.y = s1.lo;
  h.z = s2.hi; l.z = s2.lo; h.w = s3.hi; l.w = s3.lo;
  const size_t ad = packAK(n, k4, 16);
  *(half4*)(hi + ad) = h;
  *(half4*)(lo + ad) = l;
}

// -------- h0 = ie @ W_in^T + b_in, register-direct fp16x2 3-pass (one-time).
__global__ __launch_bounds__(256, 2) void h0_mfma(
    const _Float16* __restrict__ a_hi, const _Float16* __restrict__ a_lo,
    const _Float16* __restrict__ w_hi, const _Float16* __restrict__ w_lo,
    const float* __restrict__ b_in,
    _Float16* __restrict__ h_hi, _Float16* __restrict__ h_lo) {
  const int t    = threadIdx.x;
  const int bx   = blockIdx.x;                 // m block (16)
  const int by   = blockIdx.y;                 // n block (8)
  const int lane = t & 63, wid = t >> 6;
  const int wm   = (wid >> 1) * 64;
  const int wnv  = wid & 1;
  const int lc   = lane & 15, lg = lane >> 4;
  constexpr int SK = 4 * 128 * 8;              // 4096

  size_t adr_a = (size_t)bx * 16 * SK + ((size_t)lg * 128 + wm + lc) * 8;
  size_t adr_b = (size_t)by * 16 * SK + ((size_t)lg * 128 + wnv * 64 + lc) * 8;

  f32x4 acc1[4][4] = {}; f32x4 acc2[4][4] = {};
  for (int ks = 0; ks < 16; ++ks) {
    half8 ah[4], al[4], bh[4], bl[4];
#pragma unroll
    for (int mf = 0; mf < 4; ++mf) {
      ah[mf] = *(const half8*)(a_hi + adr_a + mf * 128);
      al[mf] = *(const half8*)(a_lo + adr_a + mf * 128);
    }
#pragma unroll
    for (int nf = 0; nf < 4; ++nf) {
      bh[nf] = *(const half8*)(w_hi + adr_b + nf * 128);
      bl[nf] = *(const half8*)(w_lo + adr_b + nf * 128);
    }
#pragma unroll
    for (int mf = 0; mf < 4; ++mf)
#pragma unroll
      for (int nf = 0; nf < 4; ++nf) {
        acc1[mf][nf] = __builtin_amdgcn_mfma_f32_16x16x32_f16(ah[mf], bh[nf], acc1[mf][nf], 0, 0, 0);
        acc2[mf][nf] = __builtin_amdgcn_mfma_f32_16x16x32_f16(ah[mf], bl[nf], acc2[mf][nf], 0, 0, 0);
        acc2[mf][nf] = __builtin_amdgcn_mfma_f32_16x16x32_f16(al[mf], bh[nf], acc2[mf][nf], 0, 0, 0);
      }
    adr_a += SK; adr_b += SK;
  }
#pragma unroll
  for (int mf = 0; mf < 4; ++mf)
#pragma unroll
    for (int reg = 0; reg < 4; ++reg) {
      const int gm = bx * 128 + wm + mf * 16 + lg * 4 + reg;
#pragma unroll
      for (int nf = 0; nf < 4; ++nf) {
        const int j = by * 128 + wnv * 64 + nf * 16 + lc;
        HL s = split2v(acc1[mf][nf][reg] + acc2[mf][nf][reg] * kInvLo + b_in[j]);
        const size_t ad = packAK(gm, j, 32);
        h_hi[ad] = s.hi; h_lo[ad] = s.lo;
      }
    }
}

// ------------- Eg = out_emb @ (W_ih gate-permuted)^T, fp16x2 3-pass, one-time.
__global__ __launch_bounds__(256, 2) void eg_gemm(
    const _Float16* __restrict__ oe_hi, const _Float16* __restrict__ oe_lo,
    const _Float16* __restrict__ Wg_hi, const _Float16* __restrict__ Wg_lo,
    float* __restrict__ Eg) {
  __shared__ __align__(16) _Float16 Ah[4][128][8], Al[4][128][8],
                                    Bh[4][128][8], Bl[4][128][8];
  const int t    = threadIdx.x;
  const int m0   = blockIdx.x * 128;
  const int by   = blockIdx.y;
  const int n0   = by * 128;
  const int r    = t & 127, q = t >> 7;
  const int rw   = r & 64;
  const int lane = t & 63, wid = t >> 6;
  const int wm   = (wid >> 1) * 64;
  const int wnv  = wid & 1;
  const int lc   = lane & 15, lg = lane >> 4;
  f32x4 acc1[4][4] = {}; f32x4 acc2[4][4] = {};
  for (int k0 = 0; k0 < kEout; k0 += 32) {
    const size_t oa = (size_t)(m0 + r) * kEout + k0 + q * 16;
    const size_t ob = (size_t)(n0 + r) * kEout + k0 + q * 16;
    __syncthreads();
    GLL16(oe_hi + oa,     &Ah[2*q  ][rw][0]);
    GLL16(oe_hi + oa + 8, &Ah[2*q+1][rw][0]);
    GLL16(oe_lo + oa,     &Al[2*q  ][rw][0]);
    GLL16(oe_lo + oa + 8, &Al[2*q+1][rw][0]);
    GLL16(Wg_hi + ob,     &Bh[2*q  ][rw][0]);
    GLL16(Wg_hi + ob + 8, &Bh[2*q+1][rw][0]);
    GLL16(Wg_lo + ob,     &Bl[2*q  ][rw][0]);
    GLL16(Wg_lo + ob + 8, &Bl[2*q+1][rw][0]);
    __syncthreads();
    half8 ah[4], al[4], bh[4], bl[4];
#pragma unroll
    for (int mf = 0; mf < 4; ++mf) {
      ah[mf] = *(const half8*)&Ah[lg][wm + mf*16 + lc][0];
      al[mf] = *(const half8*)&Al[lg][wm + mf*16 + lc][0];
    }
#pragma unroll
    for (int nf = 0; nf < 4; ++nf) {
      bh[nf] = *(const half8*)&Bh[lg][wnv*64 + nf*16 + lc][0];
      bl[nf] = *(const half8*)&Bl[lg][wnv*64 + nf*16 + lc][0];
    }
#pragma unroll
    for (int mf = 0; mf < 4; ++mf)
#pragma unroll
      for (int nf = 0; nf < 4; ++nf) {
        acc1[mf][nf] = __builtin_amdgcn_mfma_f32_16x16x32_f16(ah[mf], bh[nf], acc1[mf][nf], 0, 0, 0);
        acc2[mf][nf] = __builtin_amdgcn_mfma_f32_16x16x32_f16(ah[mf], bl[nf], acc2[mf][nf], 0, 0, 0);
        acc2[mf][nf] = __builtin_amdgcn_mfma_f32_16x16x32_f16(al[mf], bh[nf], acc2[mf][nf], 0, 0, 0);
      }
  }
#pragma unroll
  for (int mf = 0; mf < 4; ++mf)
#pragma unroll
    for (int reg = 0; reg < 4; ++reg) {
      const int m = m0 + wm + mf * 16 + lg * 4 + reg;
#pragma unroll
      for (int nf = 0; nf < 4; ++nf)
        Eg[(size_t)m * kNG + n0 + wnv*64 + nf*16 + lc] =
            acc1[mf][nf][reg] + acc2[mf][nf][reg] * kInvLo;
    }
}

// ----------------- Eg row kV = sos @ W_ih^T (gate-permuted cols), exact fp32
__global__ __launch_bounds__(256) void gs_row(const float* __restrict__ sos,
                                              const float* __restrict__ W_ih,
                                              float* __restrict__ Eg) {
  const int n = blockIdx.x * 256 + threadIdx.x;   // 0..4095
  const int g = (n >> 4) & 3;
  const int j = ((n >> 6) << 4) | (n & 15);
  const float* w = W_ih + (size_t)(g * kH + j) * kEout;
  float s = 0.0f;
#pragma unroll 4
  for (int k = 0; k < kEout; k += 4) {
    float4 wv = *(const float4*)&w[k];
    float4 sv = *(const float4*)&sos[k];
    s += wv.x*sv.x + wv.y*sv.y + wv.z*sv.z + wv.w*sv.w;
  }
  Eg[(size_t)kV * kNG + n] = s;
}

// --------- gates GEMM: barrier-free register-direct, full-residency tuned.
// Block 128M x 64N, 4 waves M-split (wave 32x64: 2 mf x 4 nf = 4 gates).
// launch_bounds(256,4) -> VGPR<=128 -> 4 waves/SIMD: ALL 1024 blocks
// co-resident (zero dispatch tail) + 16 waves/CU TLP for load latency.
__global__ __launch_bounds__(256, 4) void gates_lstm_mfma(
    const _Float16* __restrict__ hp_hi,  const _Float16* __restrict__ hp_lo,
    const _Float16* __restrict__ Wgp_hi, const _Float16* __restrict__ Wgp_lo,
    const float* __restrict__ Eg,        const u64* __restrict__ keys,
    const float* __restrict__ b_ih, const float* __restrict__ b_hh,
    float* __restrict__ c,
    _Float16* __restrict__ ho_hi, _Float16* __restrict__ ho_lo,
    float* __restrict__ seq, int t) {
  const int tid  = threadIdx.x;
  const int bx   = blockIdx.x;                 // m block (16)
  const int by   = blockIdx.y;                 // n block (64 x 64-col panels)
  const int m0   = bx * 128;
  const int lane = tid & 63, wid = tid >> 6;
  const int wm   = wid * 32;                   // wave m offset
  const int lc   = lane & 15, lg = lane >> 4;
  constexpr int SK = 4 * 128 * 8;              // 4096 halfs per k-step block

  size_t adr_a = (size_t)bx * 32 * SK + ((size_t)lg * 128 + wm + lc) * 8;
  size_t adr_b = (size_t)(by >> 1) * 32 * SK
               + ((size_t)lg * 128 + (by & 1) * 64 + lc) * 8;

  f32x4 acc1[2][4] = {}; f32x4 acc2[2][4] = {};
  for (int ks = 0; ks < 32; ++ks) {
    half8 ah[2], al[2], bh[4], bl[4];
#pragma unroll
    for (int mf = 0; mf < 2; ++mf) {
      ah[mf] = *(const half8*)(hp_hi + adr_a + mf * 128);
      al[mf] = *(const half8*)(hp_lo + adr_a + mf * 128);
    }
#pragma unroll
    for (int nf = 0; nf < 4; ++nf) {
      bh[nf] = *(const half8*)(Wgp_hi + adr_b + nf * 128);
      bl[nf] = *(const half8*)(Wgp_lo + adr_b + nf * 128);
    }
#pragma unroll
    for (int mf = 0; mf < 2; ++mf)
#pragma unroll
      for (int nf = 0; nf < 4; ++nf) {
        acc1[mf][nf] = __builtin_amdgcn_mfma_f32_16x16x32_f16(ah[mf], bh[nf], acc1[mf][nf], 0, 0, 0);
        acc2[mf][nf] = __builtin_amdgcn_mfma_f32_16x16x32_f16(ah[mf], bl[nf], acc2[mf][nf], 0, 0, 0);
        acc2[mf][nf] = __builtin_amdgcn_mfma_f32_16x16x32_f16(al[mf], bh[nf], acc2[mf][nf], 0, 0, 0);
      }
    adr_a += SK; adr_b += SK;
  }
  // epilogue: j = by*16 + lc; 4 n-frags = 4 gates (i,f,g,o); Eg[sym] gather;
  // packed h output; seq[t-1] write from decoded keys (by==0 blocks).
  const int j     = by * 16 + lc;
  const int nbase = by * 64 + lc;              // Eg col for nf: nbase + nf*16
  const int jks = j >> 5, jq = (j >> 3) & 3, je = j & 7;
  float bb[4];
#pragma unroll
  for (int nf = 0; nf < 4; ++nf) bb[nf] = b_ih[nf * kH + j] + b_hh[nf * kH + j];
#pragma unroll
  for (int mf = 0; mf < 2; ++mf)
#pragma unroll
    for (int reg = 0; reg < 4; ++reg) {
      const int lr = wm + mf * 16 + lg * 4 + reg;   // local row 0..127
      const int m  = m0 + lr;
      const size_t off = (size_t)m * kH + j;
      const int s = key_sym(keys[m]);               // prev-step argmax decode
      if (by == 0 && lc == 0 && t > 0)
        seq[(size_t)m * kL + (t - 1)] = (float)(s);
      const float* Erow = Eg + (size_t)s * kNG + nbase;
      const float vi = acc1[mf][0][reg] + acc2[mf][0][reg] * kInvLo + bb[0] + Erow[0];
      const float vf = acc1[mf][1][reg] + acc2[mf][1][reg] * kInvLo + bb[1] + Erow[16];
      const float vg = acc1[mf][2][reg] + acc2[mf][2][reg] * kInvLo + bb[2] + Erow[32];
      const float vo = acc1[mf][3][reg] + acc2[mf][3][reg] * kInvLo + bb[3] + Erow[48];
      const float cn = sigm(vf) * c[off] + sigm(vi) * tanhf(vg);
      const float hn = sigm(vo) * tanhf(cn);
      c[off] = cn;
      HL sp = split2v(hn);
      const size_t ad = ((((size_t)bx * 32 + jks) * 4 + jq) * 128 + lr) * 8 + je;
      ho_hi[ad] = sp.hi; ho_lo[ad] = sp.lo;
    }
}

// ----------- logits: barrier-free register-direct; 128x32 tile, grid 16x32.
// launch_bounds(256,3): all 512 blocks co-resident. Fused argmax partial via
// atomicMax(u64 sortable key) per row per block.
__global__ __launch_bounds__(256, 3) void logits_mfma(
    const _Float16* __restrict__ hp_hi, const _Float16* __restrict__ hp_lo,
    const _Float16* __restrict__ Wop_hi, const _Float16* __restrict__ Wop_lo,
    const float* __restrict__ b_out, float* __restrict__ out,
    u64* __restrict__ keys) {
  const int t    = threadIdx.x;
  const int bx   = blockIdx.x;
  const int by   = blockIdx.y;
  const int lane = t & 63, wid = t >> 6;
  const int wm   = wid * 32;
  const int lc   = lane & 15, lg = lane >> 4;
  constexpr int SKA = 4 * 128 * 8;             // 4096
  constexpr int SKB = 4 * 32 * 8;              // 1024

  size_t adr_a = (size_t)bx * 32 * SKA + ((size_t)lg * 128 + wm + lc) * 8;
  size_t adr_b = (size_t)by * 32 * SKB + ((size_t)lg * 32 + lc) * 8;

  f32x4 acc1[2][2] = {}; f32x4 acc2[2][2] = {};
#pragma unroll 2
  for (int ks = 0; ks < 32; ++ks) {
    half8 ah[2], al[2], bh[2], bl[2];
#pragma unroll
    for (int mf = 0; mf < 2; ++mf) {
      ah[mf] = *(const half8*)(hp_hi + adr_a + mf * 128);
      al[mf] = *(const half8*)(hp_lo + adr_a + mf * 128);
    }
#pragma unroll
    for (int nf = 0; nf < 2; ++nf) {
      bh[nf] = *(const half8*)(Wop_hi + adr_b + nf * 128);
      bl[nf] = *(const half8*)(Wop_lo + adr_b + nf * 128);
    }
#pragma unroll
    for (int mf = 0; mf < 2; ++mf)
#pragma unroll
      for (int nf = 0; nf < 2; ++nf) {
        acc1[mf][nf] = __builtin_amdgcn_mfma_f32_16x16x32_f16(ah[mf], bh[nf], acc1[mf][nf], 0, 0, 0);
        acc2[mf][nf] = __builtin_amdgcn_mfma_f32_16x16x32_f16(ah[mf], bl[nf], acc2[mf][nf], 0, 0, 0);
        acc2[mf][nf] = __builtin_amdgcn_mfma_f32_16x16x32_f16(al[mf], bh[nf], acc2[mf][nf], 0, 0, 0);
      }
    adr_a += SKA; adr_b += SKB;
  }
#pragma unroll
  for (int mf = 0; mf < 2; ++mf)
#pragma unroll
    for (int reg = 0; reg < 4; ++reg) {
      const int m = bx * 128 + wm + mf * 16 + lg * 4 + reg;
      float v[2];
#pragma unroll
      for (int nf = 0; nf < 2; ++nf) {
        const int n = by * 32 + nf * 16 + lc;
        v[nf] = acc1[mf][nf][reg] + acc2[mf][nf][reg] * kInvLo + b_out[n];
        out[(size_t)m * (kL * kV) + n] = v[nf];
      }
      float bv = v[0]; int bi = by * 32 + lc;
      if (v[1] > bv) { bv = v[1]; bi = by * 32 + 16 + lc; }   // strict >: first-max
#pragma unroll
      for (int off = 1; off < 16; off <<= 1) {
        const float ov = __shfl_xor(bv, off);
        const int   oi = __shfl_xor(bi, off);
        if (ov > bv || (ov == bv && oi < bi)) { bv = ov; bi = oi; }
      }
      if (lc == 0) atomicMax(&keys[m], amax_key(bv, bi));
    }
}

// --------------------------------- final step's seq write from keys[16]
__global__ __launch_bounds__(256) void final_decode(const u64* __restrict__ keys,
                                                    float* __restrict__ seq) {
  const int b = blockIdx.x * 256 + threadIdx.x;
  if (b >= kB) return;
  const u64 k = keys[b];
  seq[(size_t)b * kL + (kL - 1)] = (float)(k == 0 ? 0 : 1023 - (int)(k & 1023));
}

// ---------------------------------------------------------------------------
extern "C" void kernel_launch(void* const* d_in, const int* in_sizes, int n_in,
                              void* d_out, int out_size, void* d_ws, size_t ws_size,
                              hipStream_t stream) {
  const int*   x       = (const int*)d_in[0];
  const float* in_emb  = (const float*)d_in[1];
  const float* out_emb = (const float*)d_in[2];
  const float* W_in    = (const float*)d_in[3];
  const float* b_in    = (const float*)d_in[4];
  const float* W_ih    = (const float*)d_in[5];
  const float* b_ih    = (const float*)d_in[6];
  const float* W_hh    = (const float*)d_in[7];
  const float* b_hh    = (const float*)d_in[8];
  const float* W_out   = (const float*)d_in[9];
  const float* b_out   = (const float*)d_in[10];
  const float* sos     = (const float*)d_in[11];

  // workspace layout
  float* cb  = (float*)d_ws;                           // [B,H] fp32 cell state
  float* Eg  = cb + (size_t)kB * kH;                   // [V+1][4096] fp32
  u64*  keys = (u64*)(Eg + (size_t)(kV + 1) * kNG);    // [17][B] argmax keys
  _Float16* hp = (_Float16*)(keys + 17 * (size_t)kB);
  const size_t nBH = (size_t)kB * kH;                  // 2097152
  _Float16* hA_hi  = hp;            _Float16* hA_lo  = hp + nBH;     // packed
  _Float16* hB_hi  = hp + 2*nBH;    _Float16* hB_lo  = hp + 3*nBH;   // packed
  _Float16* Wgrm_hi = hp + 4*nBH;                       // [4096][256] row-major
  _Float16* Wgrm_lo = Wgrm_hi + (size_t)kNG*kEout;
  _Float16* Wgp_hi  = Wgrm_lo + (size_t)kNG*kEout;      // packed [4096 x 1024]
  _Float16* Wgp_lo  = Wgp_hi + (size_t)kNG*kH;
  _Float16* Wop_hi  = Wgp_lo + (size_t)kNG*kH;          // packed [1024 x 1024]
  _Float16* Wop_lo  = Wop_hi + (size_t)kV*kH;
  _Float16* oe_hi   = Wop_lo + (size_t)kV*kH;           // [1024][256] row-major
  _Float16* oe_lo   = oe_hi + (size_t)kV*kEout;
  _Float16* A0_hi   = oe_lo + (size_t)kV*kEout;         // packed [2048 x 512]
  _Float16* A0_lo   = A0_hi + (size_t)kB*kKin;
  _Float16* W0_hi   = A0_lo + (size_t)kB*kKin;          // packed [1024 x 512]
  _Float16* W0_lo   = W0_hi + (size_t)kH*kKin;

  float* seq    = (float*)d_out;                       // [B,L]
  float* logits = seq + (size_t)kB * kL;               // [B,L,V]

  init_state<<<(kB * kH) / 256, 256, 0, stream>>>(cb, keys);
  split_gates_w<<<kNG, 320, 0, stream>>>(W_ih, W_hh, Wgrm_hi, Wgrm_lo, Wgp_hi, Wgp_lo);
  split_pack_wo<<<kV, 256, 0, stream>>>(W_out, Wop_hi, Wop_lo);
  split_plain<<<(kV * kEout / 4) / 256, 256, 0, stream>>>(out_emb, oe_hi, oe_lo, kV * kEout / 4);
  pack_a0<<<kB, 128, 0, stream>>>(x, in_emb, A0_hi, A0_lo);
  pack_w0<<<kH, 128, 0, stream>>>(W_in, W0_hi, W0_lo);
  eg_gemm<<<dim3(kV / 128, kNG / 128), 256, 0, stream>>>(oe_hi, oe_lo, Wgrm_hi, Wgrm_lo, Eg);
  gs_row<<<kNG / 256, 256, 0, stream>>>(sos, W_ih, Eg);
  h0_mfma<<<dim3(kB / 128, kH / 128), 256, 0, stream>>>(A0_hi, A0_lo, W0_hi, W0_lo, b_in, hA_hi, hA_lo);

  for (int t = 0; t < kL; ++t) {
    const _Float16* hi_h = (t & 1) ? hB_hi : hA_hi;
    const _Float16* hi_l = (t & 1) ? hB_lo : hA_lo;
    _Float16* ho_h = (t & 1) ? hA_hi : hB_hi;
    _Float16* ho_l = (t & 1) ? hA_lo : hB_lo;
    gates_lstm_mfma<<<dim3(kB / 128, kNG / 64), 256, 0, stream>>>(
        hi_h, hi_l, Wgp_hi, Wgp_lo, Eg, keys + (size_t)t * kB,
        b_ih, b_hh, cb, ho_h, ho_l, seq, t);
    logits_mfma<<<dim3(kB / 128, kV / 32), 256, 0, stream>>>(
        ho_h, ho_l, Wop_hi, Wop_lo, b_out, logits + (size_t)t * kV,
        keys + (size_t)(t + 1) * kB);
  }
  final_decode<<<kB / 256, 256, 0, stream>>>(keys + 16 * (size_t)kB, seq);
}

// Round 17
// 1723.436 us; speedup vs baseline: 1.0420x; 1.0009x over previous
//
#include <hip/hip_runtime.h>
#include <math.h>

// Problem constants
constexpr int kB    = 2048;
constexpr int kA    = 8;
constexpr int kEin  = 64;
constexpr int kEout = 256;
constexpr int kH    = 1024;
constexpr int kV    = 1024;
constexpr int kL    = 16;
constexpr int kKin  = kA * kEin;      // 512
constexpr int kNG   = 4 * kH;         // 4096 gate cols
constexpr float kInvLo = 1.0f / 2048.0f;

using half8 = __attribute__((ext_vector_type(8))) _Float16;
using half4 = __attribute__((ext_vector_type(4))) _Float16;
using f32x4 = __attribute__((ext_vector_type(4))) float;
using u64   = unsigned long long;

// async global->LDS (used only by one-time eg_gemm)
#define GLL16(g, l) __builtin_amdgcn_global_load_lds(                        \
    (const __attribute__((address_space(1))) void*)(g),                      \
    (__attribute__((address_space(3))) void*)(l), 16, 0, 0)

__device__ __forceinline__ float sigm(float x) { return 1.0f / (1.0f + expf(-x)); }

// fp32 -> fp16 hi + fp16 lo (x ~= hi + lo/2048), ~22 significant bits
struct HL { _Float16 hi, lo; };
__device__ __forceinline__ HL split2v(float x) {
  HL r;
  r.hi = (_Float16)x;
  r.lo = (_Float16)((x - (float)r.hi) * 2048.0f);
  return r;
}

// Packed fragment layout (128-row blocks, NKS k-steps of 32): elem (m,k) ->
//   ((((m>>7)*NKS + (k>>5))*4 + ((k>>3)&3))*128 + (m&127))*8 + (k&7)
__device__ __forceinline__ size_t packAK(int m, int k, int nks) {
  return ((((size_t)(m >> 7) * nks + (k >> 5)) * 4 + ((k >> 3) & 3)) * 128 + (m & 127)) * 8 + (k & 7);
}

// argmax key: sortable-float major, (1023-idx) minor -> max key == numpy first-max
__device__ __forceinline__ u64 amax_key(float v, int idx) {
  unsigned b = __float_as_uint(v);
  unsigned u = (b & 0x80000000u) ? ~b : (b | 0x80000000u);
  return ((u64)u << 10) | (unsigned)(1023 - idx);
}
__device__ __forceinline__ int key_sym(u64 k) {
  return k == 0 ? kV : 1023 - (int)(k & 1023);   // 0 = never-written = SOS row
}

// ---------------------------------------------------------------- init state
__global__ __launch_bounds__(256) void init_state(float* __restrict__ c,
                                                  u64* __restrict__ keys) {
  int i = blockIdx.x * 256 + threadIdx.x;
  c[i] = 0.0f;
  if (i < 17 * kB) keys[i] = 0ull;
}

// -------------------------------------------------- plain fp32 -> hi/lo split
__global__ __launch_bounds__(256) void split_plain(const float* __restrict__ src,
                                                   _Float16* __restrict__ hi,
                                                   _Float16* __restrict__ lo,
                                                   int n4) {
  int i = blockIdx.x * 256 + threadIdx.x;
  if (i >= n4) return;
  float4 v = ((const float4*)src)[i];
  half4 h, l;
  HL s0 = split2v(v.x), s1 = split2v(v.y), s2 = split2v(v.z), s3 = split2v(v.w);
  h.x = s0.hi; l.x = s0.lo; h.y = s1.hi; l.y = s1.lo;
  h.z = s2.hi; l.z = s2.lo; h.w = s3.hi; l.w = s3.lo;
  *(half4*)(hi + (size_t)i * 4) = h;
  *(half4*)(lo + (size_t)i * 4) = l;
}

// --------------- gates weights: gate-permute + split. k<256 (W_ih part) goes
// row-major [n][256] (for eg_gemm); k>=256 (W_hh part) goes packed fragments.
__global__ __launch_bounds__(320) void split_gates_w(const float* __restrict__ W_ih,
                                                     const float* __restrict__ W_hh,
                                                     _Float16* __restrict__ rm_hi,
                                                     _Float16* __restrict__ rm_lo,
                                                     _Float16* __restrict__ p_hi,
                                                     _Float16* __restrict__ p_lo) {
  const int n  = blockIdx.x;
  const int k4 = threadIdx.x * 4;
  const int g  = (n >> 4) & 3;
  const int j  = ((n >> 6) << 4) | (n & 15);
  const int src = g * kH + j;
  float4 v = (k4 < kEout) ? *(const float4*)&W_ih[(size_t)src * kEout + k4]
                          : *(const float4*)&W_hh[(size_t)src * kH + (k4 - kEout)];
  half4 h, l;
  HL s0 = split2v(v.x), s1 = split2v(v.y), s2 = split2v(v.z), s3 = split2v(v.w);
  h.x = s0.hi; l.x = s0.lo; h.y = s1.hi; l.y = s1.lo;
  h.z = s2.hi; l.z = s2.lo; h.w = s3.hi; l.w = s3.lo;
  if (k4 < kEout) {
    *(half4*)(rm_hi + (size_t)n * kEout + k4) = h;
    *(half4*)(rm_lo + (size_t)n * kEout + k4) = l;
  } else {
    const size_t ad = packAK(n, k4 - kEout, 32);
    *(half4*)(p_hi + ad) = h;
    *(half4*)(p_lo + ad) = l;
  }
}

// ------------------- W_out -> split + packed fragments (32-row n-blocks)
__global__ __launch_bounds__(256) void split_pack_wo(const float* __restrict__ W_out,
                                                     _Float16* __restrict__ hi,
                                                     _Float16* __restrict__ lo) {
  const int n  = blockIdx.x;            // 0..1023
  const int k4 = threadIdx.x * 4;       // 0..1023
  float4 v = *(const float4*)&W_out[(size_t)n * kH + k4];
  half4 h, l;
  HL s0 = split2v(v.x), s1 = split2v(v.y), s2 = split2v(v.z), s3 = split2v(v.w);
  h.x = s0.hi; l.x = s0.lo; h.y = s1.hi; l.y = s1.lo;
  h.z = s2.hi; l.z = s2.lo; h.w = s3.hi; l.w = s3.lo;
  const size_t ad = ((((size_t)(n >> 5) * 32 + (k4 >> 5)) * 4 + ((k4 >> 3) & 3)) * 32
                     + (n & 31)) * 8 + (k4 & 7);
  *(half4*)(hi + ad) = h;
  *(half4*)(lo + ad) = l;
}

// ------------- pack A0 = in_emb[x] gathered, split, packed (K=512, 16 ks)
__global__ __launch_bounds__(128) void pack_a0(const int* __restrict__ x,
                                               const float* __restrict__ in_emb,
                                               _Float16* __restrict__ hi,
                                               _Float16* __restrict__ lo) {
  const int m  = blockIdx.x;            // 0..2047
  const int k4 = threadIdx.x * 4;       // 0..511
  const int idx = x[m * kA + (k4 >> 6)];
  float4 v = *(const float4*)&in_emb[(size_t)idx * kEin + (k4 & 63)];
  half4 h, l;
  HL s0 = split2v(v.x), s1 = split2v(v.y), s2 = split2v(v.z), s3 = split2v(v.w);
  h.x = s0.hi; l.x = s0.lo; h.y = s1.hi; l.y = s1.lo;
  h.z = s2.hi; l.z = s2.lo; h.w = s3.hi; l.w = s3.lo;
  const size_t ad = packAK(m, k4, 16);
  *(half4*)(hi + ad) = h;
  *(half4*)(lo + ad) = l;
}

// ------------- pack W_in: [1024][512] -> split packed fragments (K=512, 16 ks)
__global__ __launch_bounds__(128) void pack_w0(const float* __restrict__ W_in,
                                               _Float16* __restrict__ hi,
                                               _Float16* __restrict__ lo) {
  const int n  = blockIdx.x;            // 0..1023
  const int k4 = threadIdx.x * 4;       // 0..511
  float4 v = *(const float4*)&W_in[(size_t)n * kKin + k4];
  half4 h, l;
  HL s0 = split2v(v.x), s1 = split2v(v.y), s2 = split2v(v.z), s3 = split2v(v.w);
  h.x = s0.hi; l.x = s0.lo; h.y = s1.hi; l.y = s1.lo;
  h.z = s2.hi; l.z = s2.lo; h.w = s3.hi; l.w = s3.lo;
  const size_t ad = packAK(n, k4, 16);
  *(half4*)(hi + ad) = h;
  *(half4*)(lo + ad) = l;
}

// -------- h0 = ie @ W_in^T + b_in, register-direct fp16x2 3-pass (one-time).
__global__ __launch_bounds__(256, 2) void h0_mfma(
    const _Float16* __restrict__ a_hi, const _Float16* __restrict__ a_lo,
    const _Float16* __restrict__ w_hi, const _Float16* __restrict__ w_lo,
    const float* __restrict__ b_in,
    _Float16* __restrict__ h_hi, _Float16* __restrict__ h_lo) {
  const int t    = threadIdx.x;
  const int bx   = blockIdx.x;                 // m block (16)
  const int by   = blockIdx.y;                 // n block (8)
  const int lane = t & 63, wid = t >> 6;
  const int wm   = (wid >> 1) * 64;
  const int wnv  = wid & 1;
  const int lc   = lane & 15, lg = lane >> 4;
  constexpr int SK = 4 * 128 * 8;              // 4096

  size_t adr_a = (size_t)bx * 16 * SK + ((size_t)lg * 128 + wm + lc) * 8;
  size_t adr_b = (size_t)by * 16 * SK + ((size_t)lg * 128 + wnv * 64 + lc) * 8;

  f32x4 acc1[4][4] = {}; f32x4 acc2[4][4] = {};
  for (int ks = 0; ks < 16; ++ks) {
    half8 ah[4], al[4], bh[4], bl[4];
#pragma unroll
    for (int mf = 0; mf < 4; ++mf) {
      ah[mf] = *(const half8*)(a_hi + adr_a + mf * 128);
      al[mf] = *(const half8*)(a_lo + adr_a + mf * 128);
    }
#pragma unroll
    for (int nf = 0; nf < 4; ++nf) {
      bh[nf] = *(const half8*)(w_hi + adr_b + nf * 128);
      bl[nf] = *(const half8*)(w_lo + adr_b + nf * 128);
    }
#pragma unroll
    for (int mf = 0; mf < 4; ++mf)
#pragma unroll
      for (int nf = 0; nf < 4; ++nf) {
        acc1[mf][nf] = __builtin_amdgcn_mfma_f32_16x16x32_f16(ah[mf], bh[nf], acc1[mf][nf], 0, 0, 0);
        acc2[mf][nf] = __builtin_amdgcn_mfma_f32_16x16x32_f16(ah[mf], bl[nf], acc2[mf][nf], 0, 0, 0);
        acc2[mf][nf] = __builtin_amdgcn_mfma_f32_16x16x32_f16(al[mf], bh[nf], acc2[mf][nf], 0, 0, 0);
      }
    adr_a += SK; adr_b += SK;
  }
#pragma unroll
  for (int mf = 0; mf < 4; ++mf)
#pragma unroll
    for (int reg = 0; reg < 4; ++reg) {
      const int gm = bx * 128 + wm + mf * 16 + lg * 4 + reg;
#pragma unroll
      for (int nf = 0; nf < 4; ++nf) {
        const int j = by * 128 + wnv * 64 + nf * 16 + lc;
        HL s = split2v(acc1[mf][nf][reg] + acc2[mf][nf][reg] * kInvLo + b_in[j]);
        const size_t ad = packAK(gm, j, 32);
        h_hi[ad] = s.hi; h_lo[ad] = s.lo;
      }
    }
}

// ------------- Eg = out_emb @ (W_ih gate-permuted)^T, fp16x2 3-pass, one-time.
__global__ __launch_bounds__(256, 2) void eg_gemm(
    const _Float16* __restrict__ oe_hi, const _Float16* __restrict__ oe_lo,
    const _Float16* __restrict__ Wg_hi, const _Float16* __restrict__ Wg_lo,
    float* __restrict__ Eg) {
  __shared__ __align__(16) _Float16 Ah[4][128][8], Al[4][128][8],
                                    Bh[4][128][8], Bl[4][128][8];
  const int t    = threadIdx.x;
  const int m0   = blockIdx.x * 128;
  const int by   = blockIdx.y;
  const int n0   = by * 128;
  const int r    = t & 127, q = t >> 7;
  const int rw   = r & 64;
  const int lane = t & 63, wid = t >> 6;
  const int wm   = (wid >> 1) * 64;
  const int wnv  = wid & 1;
  const int lc   = lane & 15, lg = lane >> 4;
  f32x4 acc1[4][4] = {}; f32x4 acc2[4][4] = {};
  for (int k0 = 0; k0 < kEout; k0 += 32) {
    const size_t oa = (size_t)(m0 + r) * kEout + k0 + q * 16;
    const size_t ob = (size_t)(n0 + r) * kEout + k0 + q * 16;
    __syncthreads();
    GLL16(oe_hi + oa,     &Ah[2*q  ][rw][0]);
    GLL16(oe_hi + oa + 8, &Ah[2*q+1][rw][0]);
    GLL16(oe_lo + oa,     &Al[2*q  ][rw][0]);
    GLL16(oe_lo + oa + 8, &Al[2*q+1][rw][0]);
    GLL16(Wg_hi + ob,     &Bh[2*q  ][rw][0]);
    GLL16(Wg_hi + ob + 8, &Bh[2*q+1][rw][0]);
    GLL16(Wg_lo + ob,     &Bl[2*q  ][rw][0]);
    GLL16(Wg_lo + ob + 8, &Bl[2*q+1][rw][0]);
    __syncthreads();
    half8 ah[4], al[4], bh[4], bl[4];
#pragma unroll
    for (int mf = 0; mf < 4; ++mf) {
      ah[mf] = *(const half8*)&Ah[lg][wm + mf*16 + lc][0];
      al[mf] = *(const half8*)&Al[lg][wm + mf*16 + lc][0];
    }
#pragma unroll
    for (int nf = 0; nf < 4; ++nf) {
      bh[nf] = *(const half8*)&Bh[lg][wnv*64 + nf*16 + lc][0];
      bl[nf] = *(const half8*)&Bl[lg][wnv*64 + nf*16 + lc][0];
    }
#pragma unroll
    for (int mf = 0; mf < 4; ++mf)
#pragma unroll
      for (int nf = 0; nf < 4; ++nf) {
        acc1[mf][nf] = __builtin_amdgcn_mfma_f32_16x16x32_f16(ah[mf], bh[nf], acc1[mf][nf], 0, 0, 0);
        acc2[mf][nf] = __builtin_amdgcn_mfma_f32_16x16x32_f16(ah[mf], bl[nf], acc2[mf][nf], 0, 0, 0);
        acc2[mf][nf] = __builtin_amdgcn_mfma_f32_16x16x32_f16(al[mf], bh[nf], acc2[mf][nf], 0, 0, 0);
      }
  }
#pragma unroll
  for (int mf = 0; mf < 4; ++mf)
#pragma unroll
    for (int reg = 0; reg < 4; ++reg) {
      const int m = m0 + wm + mf * 16 + lg * 4 + reg;
#pragma unroll
      for (int nf = 0; nf < 4; ++nf)
        Eg[(size_t)m * kNG + n0 + wnv*64 + nf*16 + lc] =
            acc1[mf][nf][reg] + acc2[mf][nf][reg] * kInvLo;
    }
}

// ----------------- Eg row kV = sos @ W_ih^T (gate-permuted cols), exact fp32
__global__ __launch_bounds__(256) void gs_row(const float* __restrict__ sos,
                                              const float* __restrict__ W_ih,
                                              float* __restrict__ Eg) {
  const int n = blockIdx.x * 256 + threadIdx.x;   // 0..4095
  const int g = (n >> 4) & 3;
  const int j = ((n >> 6) << 4) | (n & 15);
  const float* w = W_ih + (size_t)(g * kH + j) * kEout;
  float s = 0.0f;
#pragma unroll 4
  for (int k = 0; k < kEout; k += 4) {
    float4 wv = *(const float4*)&w[k];
    float4 sv = *(const float4*)&sos[k];
    s += wv.x*sv.x + wv.y*sv.y + wv.z*sv.z + wv.w*sv.w;
  }
  Eg[(size_t)kV * kNG + n] = s;
}

// --------- gates GEMM: barrier-free register-direct, full-residency tuned.
// Block 128M x 64N, 4 waves M-split (wave 32x64: 2 mf x 4 nf = 4 gates).
// launch_bounds(256,4) -> VGPR<=128 -> 4 waves/SIMD: ALL 1024 blocks
// co-resident (zero dispatch tail) + 16 waves/CU TLP for load latency.
__global__ __launch_bounds__(256, 4) void gates_lstm_mfma(
    const _Float16* __restrict__ hp_hi,  const _Float16* __restrict__ hp_lo,
    const _Float16* __restrict__ Wgp_hi, const _Float16* __restrict__ Wgp_lo,
    const float* __restrict__ Eg,        const u64* __restrict__ keys,
    const float* __restrict__ b_ih, const float* __restrict__ b_hh,
    float* __restrict__ c,
    _Float16* __restrict__ ho_hi, _Float16* __restrict__ ho_lo,
    float* __restrict__ seq, int t) {
  const int tid  = threadIdx.x;
  const int bx   = blockIdx.x;                 // m block (16)
  const int by   = blockIdx.y;                 // n block (64 x 64-col panels)
  const int m0   = bx * 128;
  const int lane = tid & 63, wid = tid >> 6;
  const int wm   = wid * 32;                   // wave m offset
  const int lc   = lane & 15, lg = lane >> 4;
  constexpr int SK = 4 * 128 * 8;              // 4096 halfs per k-step block

  size_t adr_a = (size_t)bx * 32 * SK + ((size_t)lg * 128 + wm + lc) * 8;
  size_t adr_b = (size_t)(by >> 1) * 32 * SK
               + ((size_t)lg * 128 + (by & 1) * 64 + lc) * 8;

  f32x4 acc1[2][4] = {}; f32x4 acc2[2][4] = {};
  for (int ks = 0; ks < 32; ++ks) {
    half8 ah[2], al[2], bh[4], bl[4];
#pragma unroll
    for (int mf = 0; mf < 2; ++mf) {
      ah[mf] = *(const half8*)(hp_hi + adr_a + mf * 128);
      al[mf] = *(const half8*)(hp_lo + adr_a + mf * 128);
    }
#pragma unroll
    for (int nf = 0; nf < 4; ++nf) {
      bh[nf] = *(const half8*)(Wgp_hi + adr_b + nf * 128);
      bl[nf] = *(const half8*)(Wgp_lo + adr_b + nf * 128);
    }
#pragma unroll
    for (int mf = 0; mf < 2; ++mf)
#pragma unroll
      for (int nf = 0; nf < 4; ++nf) {
        acc1[mf][nf] = __builtin_amdgcn_mfma_f32_16x16x32_f16(ah[mf], bh[nf], acc1[mf][nf], 0, 0, 0);
        acc2[mf][nf] = __builtin_amdgcn_mfma_f32_16x16x32_f16(ah[mf], bl[nf], acc2[mf][nf], 0, 0, 0);
        acc2[mf][nf] = __builtin_amdgcn_mfma_f32_16x16x32_f16(al[mf], bh[nf], acc2[mf][nf], 0, 0, 0);
      }
    adr_a += SK; adr_b += SK;
  }
  // epilogue: j = by*16 + lc; 4 n-frags = 4 gates (i,f,g,o); Eg[sym] gather;
  // packed h output; seq[t-1] write from decoded keys (by==0 blocks).
  const int j     = by * 16 + lc;
  const int nbase = by * 64 + lc;              // Eg col for nf: nbase + nf*16
  const int jks = j >> 5, jq = (j >> 3) & 3, je = j & 7;
  float bb[4];
#pragma unroll
  for (int nf = 0; nf < 4; ++nf) bb[nf] = b_ih[nf * kH + j] + b_hh[nf * kH + j];
#pragma unroll
  for (int mf = 0; mf < 2; ++mf)
#pragma unroll
    for (int reg = 0; reg < 4; ++reg) {
      const int lr = wm + mf * 16 + lg * 4 + reg;   // local row 0..127
      const int m  = m0 + lr;
      const size_t off = (size_t)m * kH + j;
      const int s = key_sym(keys[m]);               // prev-step argmax decode
      if (by == 0 && lc == 0 && t > 0)
        seq[(size_t)m * kL + (t - 1)] = (float)(s);
      const float* Erow = Eg + (size_t)s * kNG + nbase;
      const float vi = acc1[mf][0][reg] + acc2[mf][0][reg] * kInvLo + bb[0] + Erow[0];
      const float vf = acc1[mf][1][reg] + acc2[mf][1][reg] * kInvLo + bb[1] + Erow[16];
      const float vg = acc1[mf][2][reg] + acc2[mf][2][reg] * kInvLo + bb[2] + Erow[32];
      const float vo = acc1[mf][3][reg] + acc2[mf][3][reg] * kInvLo + bb[3] + Erow[48];
      const float cn = sigm(vf) * c[off] + sigm(vi) * tanhf(vg);
      const float hn = sigm(vo) * tanhf(cn);
      c[off] = cn;
      HL sp = split2v(hn);
      const size_t ad = ((((size_t)bx * 32 + jks) * 4 + jq) * 128 + lr) * 8 + je;
      ho_hi[ad] = sp.hi; ho_lo[ad] = sp.lo;
    }
}

// ----------- logits: barrier-free register-direct; 128x32 tile, grid 16x32.
// launch_bounds(256,3): all 512 blocks co-resident. Fused argmax partial via
// atomicMax(u64 sortable key) per row per block.
__global__ __launch_bounds__(256, 3) void logits_mfma(
    const _Float16* __restrict__ hp_hi, const _Float16* __restrict__ hp_lo,
    const _Float16* __restrict__ Wop_hi, const _Float16* __restrict__ Wop_lo,
    const float* __restrict__ b_out, float* __restrict__ out,
    u64* __restrict__ keys) {
  const int t    = threadIdx.x;
  const int bx   = blockIdx.x;
  const int by   = blockIdx.y;
  const int lane = t & 63, wid = t >> 6;
  const int wm   = wid * 32;
  const int lc   = lane & 15, lg = lane >> 4;
  constexpr int SKA = 4 * 128 * 8;             // 4096
  constexpr int SKB = 4 * 32 * 8;              // 1024

  size_t adr_a = (size_t)bx * 32 * SKA + ((size_t)lg * 128 + wm + lc) * 8;
  size_t adr_b = (size_t)by * 32 * SKB + ((size_t)lg * 32 + lc) * 8;

  f32x4 acc1[2][2] = {}; f32x4 acc2[2][2] = {};
#pragma unroll 2
  for (int ks = 0; ks < 32; ++ks) {
    half8 ah[2], al[2], bh[2], bl[2];
#pragma unroll
    for (int mf = 0; mf < 2; ++mf) {
      ah[mf] = *(const half8*)(hp_hi + adr_a + mf * 128);
      al[mf] = *(const half8*)(hp_lo + adr_a + mf * 128);
    }
#pragma unroll
    for (int nf = 0; nf < 2; ++nf) {
      bh[nf] = *(const half8*)(Wop_hi + adr_b + nf * 128);
      bl[nf] = *(const half8*)(Wop_lo + adr_b + nf * 128);
    }
#pragma unroll
    for (int mf = 0; mf < 2; ++mf)
#pragma unroll
      for (int nf = 0; nf < 2; ++nf) {
        acc1[mf][nf] = __builtin_amdgcn_mfma_f32_16x16x32_f16(ah[mf], bh[nf], acc1[mf][nf], 0, 0, 0);
        acc2[mf][nf] = __builtin_amdgcn_mfma_f32_16x16x32_f16(ah[mf], bl[nf], acc2[mf][nf], 0, 0, 0);
        acc2[mf][nf] = __builtin_amdgcn_mfma_f32_16x16x32_f16(al[mf], bh[nf], acc2[mf][nf], 0, 0, 0);
      }
    adr_a += SKA; adr_b += SKB;
  }
#pragma unroll
  for (int mf = 0; mf < 2; ++mf)
#pragma unroll
    for (int reg = 0; reg < 4; ++reg) {
      const int m = bx * 128 + wm + mf * 16 + lg * 4 + reg;
      float v[2];
#pragma unroll
      for (int nf = 0; nf < 2; ++nf) {
        const int n = by * 32 + nf * 16 + lc;
        v[nf] = acc1[mf][nf][reg] + acc2[mf][nf][reg] * kInvLo + b_out[n];
        out[(size_t)m * (kL * kV) + n] = v[nf];
      }
      float bv = v[0]; int bi = by * 32 + lc;
      if (v[1] > bv) { bv = v[1]; bi = by * 32 + 16 + lc; }   // strict >: first-max
#pragma unroll
      for (int off = 1; off < 16; off <<= 1) {
        const float ov = __shfl_xor(bv, off);
        const int   oi = __shfl_xor(bi, off);
        if (ov > bv || (ov == bv && oi < bi)) { bv = ov; bi = oi; }
      }
      if (lc == 0) atomicMax(&keys[m], amax_key(bv, bi));
    }
}

// --------------------------------- final step's seq write from keys[16]
__global__ __launch_bounds__(256) void final_decode(const u64* __restrict__ keys,
                                                    float* __restrict__ seq) {
  const int b = blockIdx.x * 256 + threadIdx.x;
  if (b >= kB) return;
  const u64 k = keys[b];
  seq[(size_t)b * kL + (kL - 1)] = (float)(k == 0 ? 0 : 1023 - (int)(k & 1023));
}

// ---------------------------------------------------------------------------
extern "C" void kernel_launch(void* const* d_in, const int* in_sizes, int n_in,
                              void* d_out, int out_size, void* d_ws, size_t ws_size,
                              hipStream_t stream) {
  const int*   x       = (const int*)d_in[0];
  const float* in_emb  = (const float*)d_in[1];
  const float* out_emb = (const float*)d_in[2];
  const float* W_in    = (const float*)d_in[3];
  const float* b_in    = (const float*)d_in[4];
  const float* W_ih    = (const float*)d_in[5];
  const float* b_ih    = (const float*)d_in[6];
  const float* W_hh    = (const float*)d_in[7];
  const float* b_hh    = (const float*)d_in[8];
  const float* W_out   = (const float*)d_in[9];
  const float* b_out   = (const float*)d_in[10];
  const float* sos     = (const float*)d_in[11];

  // workspace layout
  float* cb  = (float*)d_ws;                           // [B,H] fp32 cell state
  float* Eg  = cb + (size_t)kB * kH;                   // [V+1][4096] fp32
  u64*  keys = (u64*)(Eg + (size_t)(kV + 1) * kNG);    // [17][B] argmax keys
  _Float16* hp = (_Float16*)(keys + 17 * (size_t)kB);
  const size_t nBH = (size_t)kB * kH;                  // 2097152
  _Float16* hA_hi  = hp;            _Float16* hA_lo  = hp + nBH;     // packed
  _Float16* hB_hi  = hp + 2*nBH;    _Float16* hB_lo  = hp + 3*nBH;   // packed
  _Float16* Wgrm_hi = hp + 4*nBH;                       // [4096][256] row-major
  _Float16* Wgrm_lo = Wgrm_hi + (size_t)kNG*kEout;
  _Float16* Wgp_hi  = Wgrm_lo + (size_t)kNG*kEout;      // packed [4096 x 1024]
  _Float16* Wgp_lo  = Wgp_hi + (size_t)kNG*kH;
  _Float16* Wop_hi  = Wgp_lo + (size_t)kNG*kH;          // packed [1024 x 1024]
  _Float16* Wop_lo  = Wop_hi + (size_t)kV*kH;
  _Float16* oe_hi   = Wop_lo + (size_t)kV*kH;           // [1024][256] row-major
  _Float16* oe_lo   = oe_hi + (size_t)kV*kEout;
  _Float16* A0_hi   = oe_lo + (size_t)kV*kEout;         // packed [2048 x 512]
  _Float16* A0_lo   = A0_hi + (size_t)kB*kKin;
  _Float16* W0_hi   = A0_lo + (size_t)kB*kKin;          // packed [1024 x 512]
  _Float16* W0_lo   = W0_hi + (size_t)kH*kKin;

  float* seq    = (float*)d_out;                       // [B,L]
  float* logits = seq + (size_t)kB * kL;               // [B,L,V]

  init_state<<<(kB * kH) / 256, 256, 0, stream>>>(cb, keys);
  split_gates_w<<<kNG, 320, 0, stream>>>(W_ih, W_hh, Wgrm_hi, Wgrm_lo, Wgp_hi, Wgp_lo);
  split_pack_wo<<<kV, 256, 0, stream>>>(W_out, Wop_hi, Wop_lo);
  split_plain<<<(kV * kEout / 4) / 256, 256, 0, stream>>>(out_emb, oe_hi, oe_lo, kV * kEout / 4);
  pack_a0<<<kB, 128, 0, stream>>>(x, in_emb, A0_hi, A0_lo);
  pack_w0<<<kH, 128, 0, stream>>>(W_in, W0_hi, W0_lo);
  eg_gemm<<<dim3(kV / 128, kNG / 128), 256, 0, stream>>>(oe_hi, oe_lo, Wgrm_hi, Wgrm_lo, Eg);
  gs_row<<<kNG / 256, 256, 0, stream>>>(sos, W_ih, Eg);
  h0_mfma<<<dim3(kB / 128, kH / 128), 256, 0, stream>>>(A0_hi, A0_lo, W0_hi, W0_lo, b_in, hA_hi, hA_lo);

  for (int t = 0; t < kL; ++t) {
    const _Float16* hi_h = (t & 1) ? hB_hi : hA_hi;
    const _Float16* hi_l = (t & 1) ? hB_lo : hA_lo;
    _Float16* ho_h = (t & 1) ? hA_hi : hB_hi;
    _Float16* ho_l = (t & 1) ? hA_lo : hB_lo;
    gates_lstm_mfma<<<dim3(kB / 128, kNG / 64), 256, 0, stream>>>(
        hi_h, hi_l, Wgp_hi, Wgp_lo, Eg, keys + (size_t)t * kB,
        b_ih, b_hh, cb, ho_h, ho_l, seq, t);
    logits_mfma<<<dim3(kB / 128, kV / 32), 256, 0, stream>>>(
        ho_h, ho_l, Wop_hi, Wop_lo, b_out, logits + (size_t)t * kV,
        keys + (size_t)(t + 1) * kB);
  }
  final_decode<<<kB / 256, 256, 0, stream>>>(keys + 16 * (size_t)kB, seq);
}